// Round 9
// baseline (110.287 us; speedup 1.0000x reference)
//
#include <hip/hip_runtime.h>
#include <stdint.h>

// DiscreteMarkovDynamics: 5-step Markov jump sim, B=32, L=4096, V=512.
// R1-R4: table precompute, reject bound, fused build -> 121 us.
// R5: zoned work-steal REGRESSED (~10ns per serialized same-line dev atomic).
// R6: 2-wave blocks + ILP categorical -> 116 us (markov 45).
// R7: static 2 chunks/wave REGRESSED (no backfill).
// R8: 2048x256, LDS-counter chunk pulling -> 109 us (markov ~45). PASSED x2.
// R9/R10: in-block two-phase queue -> 3 contentless infra exceptions.
// R12: 2x per-block pool -> NULL. R13: pairing + slim reduce -> NULL.
// R14: 8-partition global chunk-pop REGRESSED (atomics + line-split locality).
// R15: 8192x128 oversubscribed HW backfill -> NULL (markov 46-50).
//   => FIVE schedulers pinned at ~45 us. The invariant: the serial unit is
//   the CHUNK (8 positions serial on one wave). Issue floor ~22 us (measured
//   VALU work); the rest is the max-chunk serial tail (~10-15 cats ~ 13 us)
//   ground by lone waves while the machine drains. No chunk-granule
//   scheduler can fix it; R13 can't pair a lone chain.
// R16: position-granule via scan/compact/chain, two plain kernels:
//   scan_kernel: R8 scan, writes inactive x_out (77%), compacts active
//     positions to an 8-segment global queue (u16 rel-idx; ONE aggregated
//     atomic per block -> 128/line, ~1.3 us overlapped; R5 math safe).
//   chain_kernel: 2048x256 one-ramp; 1024 waves/segment stride entries;
//     each wave = single position-chain (finest legal serial unit), body
//     byte-identical to R8. Serial tail: max-chunk -> max-chain (~4 us).

#define VOCAB  512
#define EMB    256
#define HID    64
#define NPOS   (32 * 4096)   // B*L = 131072
#define STEPS  5
#define PPW    8             // positions per chunk; PPW*STEPS=40 <= 64 lanes
#define CHUNKS (NPOS / PPW)  // 16384
#define NSEG   8             // queue segments
#define SEGPOS (NPOS / NSEG) // 16384 positions per segment
#define SCANB  1024          // scan blocks (x256: 4 waves x 4 chunks = 128 pos)
#define CHAINB 2048          // chain blocks (x256 = 8192 waves, 1024/segment)

// Exact mirror of jax._src.prng.threefry2x32 (20 rounds).
__host__ __device__ __forceinline__ void tf2x32(uint32_t k0, uint32_t k1,
                                                uint32_t x0, uint32_t x1,
                                                uint32_t& o0, uint32_t& o1) {
  uint32_t ks2 = k0 ^ k1 ^ 0x1BD11BDAu;
  x0 += k0; x1 += k1;
#define TFR(r) { x0 += x1; x1 = (x1 << (r)) | (x1 >> (32 - (r))); x1 ^= x0; }
  TFR(13) TFR(15) TFR(26) TFR(6)
  x0 += k1;  x1 += ks2 + 1u;
  TFR(17) TFR(29) TFR(16) TFR(24)
  x0 += ks2; x1 += k0 + 2u;
  TFR(13) TFR(15) TFR(26) TFR(6)
  x0 += k0;  x1 += k1 + 3u;
  TFR(17) TFR(29) TFR(16) TFR(24)
  x0 += k1;  x1 += ks2 + 4u;
  TFR(13) TFR(15) TFR(26) TFR(6)
  x0 += ks2; x1 += k0 + 5u;
#undef TFR
  o0 = x0; o1 = x1;
}

struct Keys {
  uint32_t k1a[STEPS], k1b[STEPS];  // categorical (gumbel) keys per step
  uint32_t k2a[STEPS], k2b[STEPS];  // accept-uniform keys per step
};

// Fused table build (R8 body + segment-counter zeroing; a few us in-graph).
__global__ __launch_bounds__(512)
void build_table(const float* __restrict__ emb,
                 const float* __restrict__ W1,
                 const float* __restrict__ b1,
                 const float* __restrict__ W2,
                 const float* __restrict__ b2,
                 float* __restrict__ I,
                 float* __restrict__ pthr,
                 int* __restrict__ gcnt) {
  const int s   = blockIdx.x;
  const int tid = threadIdx.x;
  __shared__ double part[8][HID];
  __shared__ double hd[HID];
  __shared__ float  redmax[8];

  // Zero the 8 segment counters (256B-spaced lines; stream order -> visible).
  if (s < NSEG && tid == 0) gcnt[s * 64] = 0;

  const int hid = tid & (HID - 1);
  const int kq  = tid >> 6;               // 0..7, k = kq + 8*i
  const float* e = emb + s * EMB;
  double acc = 0.0;
#pragma unroll
  for (int ib = 0; ib < 32; ib += 16) {   // two 16-wide batches
    float ev[16], wv[16];
#pragma unroll
    for (int i = 0; i < 16; ++i) {        // 32 loads issued together
      const int k = kq + 8 * (ib + i);
      ev[i] = e[k];
      wv[i] = W1[k * HID + hid];
    }
#pragma unroll
    for (int i = 0; i < 16; ++i)          // same order as R4's k-loop
      acc += (double)ev[i] * (double)wv[i];
  }
  part[kq][hid] = acc;
  __syncthreads();
  if (kq == 0) {
    const double a = ((part[0][hid] + part[1][hid]) + (part[2][hid] + part[3][hid]))
                   + ((part[4][hid] + part[5][hid]) + (part[6][hid] + part[7][hid]));
    const float m = (float)a + b1[hid];
    hd[hid] = (double)(m > 0.0f ? m : 0.0f);   // relu
  }
  __syncthreads();

  double acc2 = 0.0;
#pragma unroll
  for (int kb = 0; kb < HID; kb += 16) {  // four 16-wide batches
    float wv[16];
#pragma unroll
    for (int i = 0; i < 16; ++i)
      wv[i] = W2[(kb + i) * VOCAB + tid]; // coalesced, 16 in flight
#pragma unroll
    for (int i = 0; i < 16; ++i)          // same serial order as before
      acc2 += hd[kb + i] * (double)wv[i];
  }
  const float val = (float)acc2 + b2[tid];
  I[s * VOCAB + tid] = val;

  float lmax = val;                        // max is order-insensitive
  for (int off = 32; off > 0; off >>= 1)
    lmax = fmaxf(lmax, __shfl_xor(lmax, off, 64));
  if ((tid & 63) == 0) redmax[tid >> 6] = lmax;
  __syncthreads();
  if (tid == 0) {
    float m = redmax[0];
#pragma unroll
    for (int i = 1; i < 8; ++i) m = fmaxf(m, redmax[i]);
    const float z = (-m) * 0.01f;          // same chain as accept path
    pthr[s] = 1.0f - (float)exp((double)z);// monotone => safe reject bound
  }
}

// Scan: 1024 blocks x 256. Block b covers positions [b*128, b*128+128)
// (16 chunks; 4 per wave, static). Inactive positions written directly
// (provably unchanged, R2 bound); active positions compacted to the global
// queue with ONE aggregated atomic per block.
__global__ __launch_bounds__(256)
void scan_kernel(const int* __restrict__ x_in,
                 const float* __restrict__ pthr,
                 int* __restrict__ x_out,
                 int* __restrict__ gcnt,
                 unsigned short* __restrict__ queue,
                 Keys K) {
  __shared__ int lcount;
  __shared__ int lbase;
  __shared__ int lpos[128];
  if (threadIdx.x == 0) lcount = 0;
  __syncthreads();

  const int lane = threadIdx.x & 63;
  const int wid  = threadIdx.x >> 6;       // 0..3
  const int qp = lane / 5;                 // lane q -> (position, step)
  const int qt = lane - qp * 5;
  const int b = blockIdx.x;

#pragma unroll
  for (int cc = 0; cc < 4; ++cc) {
    const int chunk = b * 16 + wid * 4 + cc;
    const int base = chunk * PPW;

    const int scur = (lane < PPW) ? x_in[base + lane] : 0;
    const float pv = (lane < PPW) ? pthr[scur] : 0.0f;

    float u40 = 0.0f;                      // bit-exact R8 scan uniforms
    if (lane < PPW * STEPS) {
      uint32_t w0, w1;
      tf2x32(K.k2a[qt], K.k2b[qt], 0u, (uint32_t)(base + qp), w0, w1);
      u40 = __uint_as_float((((w0 ^ w1) >> 9) | 0x3f800000u)) - 1.0f;
    }
    const float pq = __shfl(pv, qp, 64);
    const unsigned long long mask =
        __ballot((lane < PPW * STEPS) && (u40 < pq));

    const int sh = (lane < PPW) ? lane * 5 : 0;
    const bool act = (lane < PPW) && (((mask >> sh) & 0x1Full) != 0ull);
    if (lane < PPW && !act) x_out[base + lane] = scur;  // provably unchanged
    if (lane < PPW && act) {
      const int o = atomicAdd(&lcount, 1);              // LDS atomic: cheap
      lpos[o] = base + lane;
    }
  }
  __syncthreads();
  const int seg = b >> 7;                  // 128 blocks per segment
  if (threadIdx.x == 0) lbase = atomicAdd(&gcnt[seg * 64], lcount);
  __syncthreads();
  const int lb = lbase, lc = lcount;
  for (int i = threadIdx.x; i < lc; i += 256)
    queue[seg * SEGPOS + lb + i] = (unsigned short)(lpos[i] - seg * SEGPOS);
}

// Chain: 2048 blocks x 256 = 8192 waves, one-ramp full residency. Wave W
// serves segment W>>10, striding its queue entries by 1024. Each entry is a
// single position-chain; body byte-identical to R8.
__global__ __launch_bounds__(256)
void chain_kernel(const int* __restrict__ x_in,
                  const float* __restrict__ I,
                  const float* __restrict__ pthr,
                  int* __restrict__ x_out,
                  const int* __restrict__ gcnt,
                  const unsigned short* __restrict__ queue,
                  Keys K) {
  const int lane = threadIdx.x & 63;
  const int W = blockIdx.x * 4 + (threadIdx.x >> 6);
  const int seg = W >> 10;
  const int cnt = gcnt[seg * 64];
  const float TINYF = 1.17549435e-38f;

  for (int i = (W & 1023); i < cnt; i += 1024) {
    const int pos = seg * SEGPOS + (int)queue[seg * SEGPOS + i];

    int s = x_in[pos];                     // wave-uniform broadcast load
    // Re-derive this position's 5 accept uniforms (bit-identical to scan).
    float u5 = 0.0f;
    if (lane < STEPS) {
      uint32_t w0, w1;
      tf2x32(K.k2a[lane], K.k2b[lane], 0u, (uint32_t)pos, w0, w1);
      u5 = __uint_as_float((((w0 ^ w1) >> 9) | 0x3f800000u)) - 1.0f;
    }
    const float pv0 = pthr[s];
    unsigned mask5 =
        (unsigned)(__ballot(lane < STEPS && u5 < pv0) & 0x1Full);

    while (mask5) {
      const int t = __builtin_ctz(mask5);               // wave-uniform
      mask5 &= mask5 - 1;

      // --- Full categorical (bit-identical math; ILP-batched, as R8) ---
      const float* row = I + s * VOCAB;
      float rv[8];
#pragma unroll
      for (int j = 0; j < 8; ++j)               // prefetch row values (L2)
        rv[j] = row[lane + (j << 6)];

      const uint32_t fbase = ((uint32_t)pos << 9) + (uint32_t)lane;
      uint32_t bits[8];
#pragma unroll
      for (int j = 0; j < 8; ++j) {             // 8 independent threefry
        uint32_t w0, w1;
        tf2x32(K.k1a[t], K.k1b[t], 0u, fbase + ((uint32_t)j << 6), w0, w1);
        bits[j] = w0 ^ w1;
      }

      float best = -__builtin_inff();
      float rbest = 0.0f;                        // row value of the winner
      int bidx = 0;
#pragma unroll
      for (int j = 0; j < 8; ++j) {             // 8 independent gumbel chains
        float ufv = __uint_as_float((bits[j] >> 9) | 0x3f800000u) - 1.0f;
        if (ufv == 0.0f) ufv = TINYF;
        const float g = -logf(-logf(ufv));
        const int v = lane + (j << 6);
        if (v != s) {
          const float val = rv[j] + g;
          if (val > best) { best = val; bidx = v; rbest = rv[j]; }
        }
      }
      for (int off = 32; off > 0; off >>= 1) {
        const float ob = __shfl_xor(best, off, 64);
        const int   oi = __shfl_xor(bidx, off, 64);
        const float orv = __shfl_xor(rbest, off, 64);
        if (ob > best || (ob == best && oi < bidx)) {
          best = ob; bidx = oi; rbest = orv;
        }
      }
      bidx = __builtin_amdgcn_readfirstlane(bidx);
      const float rate = rbest;                 // == row[bidx], no L2 load
      const float z = (-rate) * 0.01f;
      const float pacc = 1.0f - (float)exp((double)z);  // CR fp32 exp
      const float u = __shfl(u5, t, 64);
      if (u < pacc) {
        s = bidx;                               // accept jump (wave-uniform)
        const float pnew = pthr[bidx];          // scalar (bidx uniform)
        // Re-evaluate FUTURE steps under the new state (same algebra as R8).
        mask5 = ((unsigned)(__ballot(lane < STEPS && u5 < pnew) & 0x1Full))
                & ~((1u << (t + 1)) - 1u);
      }
    }
    if (lane == 0) x_out[pos] = s;
  }
}

extern "C" void kernel_launch(void* const* d_in, const int* in_sizes, int n_in,
                              void* d_out, int out_size, void* d_ws, size_t ws_size,
                              hipStream_t stream) {
  const int*   x   = (const int*)d_in[0];
  const float* emb = (const float*)d_in[1];
  const float* W1  = (const float*)d_in[2];
  const float* b1  = (const float*)d_in[3];
  const float* W2  = (const float*)d_in[4];
  const float* b2  = (const float*)d_in[5];
  // Workspace layout (1.26 MiB total):
  float* I = (float*)d_ws;                                       // 1 MiB
  float* pthr = (float*)((char*)d_ws + 1048576);                 // 2 KiB
  int*   gcnt = (int*)((char*)d_ws + 1050624);                   // 8x256 B
  unsigned short* queue = (unsigned short*)((char*)d_ws + 1052672); // 256 KiB
  int* out = (int*)d_out;

  // Host-side key derivation (partitionable scheme):
  //   key(42) = (0,42); split -> S_t = tf(key,(0,t)); (k1,k2) = tf(S_t,(0,j))
  Keys K;
  for (int t = 0; t < STEPS; ++t) {
    uint32_t Sa, Sb;
    tf2x32(0u, 42u, 0u, (uint32_t)t, Sa, Sb);
    tf2x32(Sa, Sb, 0u, 0u, K.k1a[t], K.k1b[t]);
    tf2x32(Sa, Sb, 0u, 1u, K.k2a[t], K.k2b[t]);
  }

  build_table<<<VOCAB, 512, 0, stream>>>(emb, W1, b1, W2, b2, I, pthr, gcnt);
  scan_kernel<<<SCANB, 256, 0, stream>>>(x, pthr, out, gcnt, queue, K);
  chain_kernel<<<CHAINB, 256, 0, stream>>>(x, I, pthr, out, gcnt, queue, K);
}